// Round 4
// baseline (706.137 us; speedup 1.0000x reference)
//
#include <hip/hip_runtime.h>
#include <hip/hip_bf16.h>
#include <stdint.h>

// R4: fp32 inputs hard-coded (R1-R3 FETCH arithmetic proves fp32).
// Main layers l1..l7: block = (dg: DT=8 d's, og: 16 o's, bg: b-split only for
// small L3-resident layers). Full batch per weight-slice for l1,l2 (weights
// read exactly once). Full-line weight staging: run (o,c) = 16 fp32 = 64 B.
// LDS W tile [plane=(d_loc,t)][o 16][c 16 pad->20], plane stride 324 u16.
// MFMA 16x16x32 bf16 (verified layouts), k = t*16 + c. Direct bf16 relu-store
// (no atomics/memset/fin for l1..l7). Tails l8,l9 + epi: proven R2 path.

#define B_   128
#define H_   256
#define OUT_ 10
#define ROWP  20              // u16 per o-row (16 c + 4 pad) -> 40 B, 10-dword stride
#define PLANE 324             // u16 per (d,t) plane: 16*20 + 4  (8-B aligned)

typedef __attribute__((ext_vector_type(4))) float floatx4;
typedef __attribute__((ext_vector_type(8))) short shortx8;
typedef __attribute__((ext_vector_type(4))) short shortx4;

__device__ __forceinline__ float bf2f(unsigned short u){
    union { unsigned int u; float f; } c; c.u = ((unsigned int)u) << 16; return c.f;
}
__device__ __forceinline__ unsigned short f2bf(float f){
    union { float f; unsigned int u; } c; c.f = f;
    unsigned int x = c.u;
    x += 0x7FFFu + ((x >> 16) & 1u);
    return (unsigned short)(x >> 16);
}

// ---------------------------------------------------------------------------
// Layer 0: A1[p=d][b][o] = relu(sum_{c,t} x[b,c,2d+t]*w0[o,c,d,t]) * (1/sqrt(3))
__global__ __launch_bounds__(256) void l0_kernel(const float* __restrict__ x,
        const float* __restrict__ w, unsigned short* __restrict__ A1){
    __shared__ float Xs[128*6];
    const int d = blockIdx.x;
    const int tid = threadIdx.x;
    for (int i = tid; i < 384; i += 256){
        int b = i / 3, c = i - b*3;
        const float* xf = x + (b*3+c)*1024 + 2*d;
        Xs[b*6 + c*2] = xf[0]; Xs[b*6 + c*2 + 1] = xf[1];
    }
    __syncthreads();
    const int o = tid;
    float wr[6];
    #pragma unroll
    for (int c = 0; c < 3; ++c){
        const float* wf = w + ((o*3+c)*512 + d)*2;
        wr[c*2] = wf[0]; wr[c*2+1] = wf[1];
    }
    const float s3 = 0.57735026918962576f;
    for (int b = 0; b < 128; ++b){
        float s = 0.f;
        #pragma unroll
        for (int j = 0; j < 6; ++j) s += Xs[b*6 + j] * wr[j];
        A1[d*32768 + b*256 + o] = f2bf(fmaxf(s, 0.f) * s3);
    }
}

// ---------------------------------------------------------------------------
// Main layer. MT = m-tiles per block (b-tile = 16*MT, bsplit = 8/MT).
// DPW = d per wave, DT = 4*DPW. o-tile 16. K = 512 in-block (16 steps of 32).
// grid = (8/MT) * dgN * 16,  bi = og + 16*(dg + dgN*bg).
template<int MT, int DPW>
__global__ __launch_bounds__(256, 2) void layer4_k(
        const unsigned short* __restrict__ Ain, const float* __restrict__ wv,
        unsigned short* __restrict__ out, int dl, int dgN){
    constexpr int DT = 4*DPW;
    __shared__ unsigned short Wt[2*DT*PLANE];
    const int tid = threadIdx.x;
    const int lane = tid & 63, wv_ = tid >> 6;
    const int mr = lane & 15, g = lane >> 4;
    const int tI = g >> 1, chI = g & 1;
    int bi = blockIdx.x;
    const int og = bi & 15; bi >>= 4;
    const int dg = bi % dgN; const int bg = bi / dgN;
    const int d0 = dg * DT, o0 = og * 16, b0 = bg * (16*MT);

    floatx4 acc[MT][DPW];
    #pragma unroll
    for (int m = 0; m < MT; ++m)
        #pragma unroll
        for (int dd = 0; dd < DPW; ++dd)
            acc[m][dd] = (floatx4){0.f,0.f,0.f,0.f};

    for (int s = 0; s < 16; ++s){
        const int c0 = s << 4;
        // ---- stage W: 256 runs (16 o x 16 c), each run = 16 fp32 = one 64-B line
        {
            constexpr int PARTS = DT/2;            // float4 parts per run
            #pragma unroll
            for (int i = 0; i < PARTS; ++i){
                int task = i*256 + tid;
                int part = task % PARTS;
                int run  = task / PARTS;
                int cl = run & 15, ol = run >> 4;
                const float* src = wv + ((size_t)((o0+ol)*256 + c0+cl))*(2*dl) + d0*2 + part*4;
                float4 v = *(const float4*)src;
                int off = ol*ROWP + cl;
                int pb = part*4;
                Wt[(pb+0)*PLANE + off] = f2bf(v.x);
                Wt[(pb+1)*PLANE + off] = f2bf(v.y);
                Wt[(pb+2)*PLANE + off] = f2bf(v.z);
                Wt[(pb+3)*PLANE + off] = f2bf(v.w);
            }
        }
        __syncthreads();
        // ---- B frags from LDS (two 8-B reads, conflict-free)
        shortx8 bfr[DPW];
        #pragma unroll
        for (int dd = 0; dd < DPW; ++dd){
            int pl = (wv_*DPW + dd)*2 + tI;
            int boff = pl*PLANE + mr*ROWP + chI*8;
            shortx4 lo = *(const shortx4*)(Wt + boff);
            shortx4 hi = *(const shortx4*)(Wt + boff + 4);
            shortx8 bb;
            bb[0]=lo[0]; bb[1]=lo[1]; bb[2]=lo[2]; bb[3]=lo[3];
            bb[4]=hi[0]; bb[5]=hi[1]; bb[6]=hi[2]; bb[7]=hi[3];
            bfr[dd] = bb;
        }
        // ---- A frags direct from global (16-B contiguous per lane) + MFMA
        #pragma unroll
        for (int m = 0; m < MT; ++m){
            #pragma unroll
            for (int dd = 0; dd < DPW; ++dd){
                int d = d0 + wv_*DPW + dd;
                const unsigned short* ap = Ain
                    + ((size_t)(2*d + tI)*128 + b0 + m*16 + mr)*256 + c0 + chI*8;
                uint4 u = *(const uint4*)ap;
                shortx8 af = *(const shortx8*)&u;
                acc[m][dd] = __builtin_amdgcn_mfma_f32_16x16x32_bf16(af, bfr[dd], acc[m][dd], 0,0,0);
            }
        }
        __syncthreads();
    }
    // ---- epilogue: D row g*4+r -> b, col mr -> o. relu * 1/16 -> bf16
    #pragma unroll
    for (int m = 0; m < MT; ++m)
        #pragma unroll
        for (int dd = 0; dd < DPW; ++dd){
            int d = d0 + wv_*DPW + dd;
            #pragma unroll
            for (int r = 0; r < 4; ++r){
                int b = b0 + m*16 + g*4 + r;
                size_t idx = ((size_t)d*128 + b)*256 + o0 + mr;
                out[idx] = f2bf(fmaxf(acc[m][dd][r], 0.f) * 0.0625f);
            }
        }
}

// ---------------------------------------------------------------------------
// Tail layers (dl<=2): gather (weights <=2MB, L2-resident), atomic fp32 out.
__global__ __launch_bounds__(256) void tail_k(const unsigned short* __restrict__ Ain,
        const float* __restrict__ wF, float* __restrict__ outS, int dl, int ksplit){
    int id = blockIdx.x;
    int d = id % dl; int t2 = id / dl;
    int ob = t2 & 3; int ksid = t2 >> 2;
    const int KSEG = 512 / ksplit;
    const int k0s = ksid * KSEG;
    const int lane = threadIdx.x & 63, wv2 = threadIdx.x >> 6;
    const int mr = lane & 15, kg = lane >> 4;
    floatx4 acc[2][4];
    #pragma unroll
    for (int mi = 0; mi < 2; ++mi)
        #pragma unroll
        for (int ni = 0; ni < 4; ++ni) acc[mi][ni] = (floatx4){0.f,0.f,0.f,0.f};
    for (int k0 = k0s; k0 < k0s + KSEG; k0 += 32){
        int c0 = (k0 >> 1) + kg*4;
        shortx8 af[2];
        #pragma unroll
        for (int mi = 0; mi < 2; ++mi){
            int b = wv2*32 + mi*16 + mr;
            #pragma unroll
            for (int cc = 0; cc < 4; ++cc){
                af[mi][2*cc]   = (short)Ain[(2*d)*32768   + b*256 + c0 + cc];
                af[mi][2*cc+1] = (short)Ain[(2*d+1)*32768 + b*256 + c0 + cc];
            }
        }
        shortx8 bf_[4];
        #pragma unroll
        for (int ni = 0; ni < 4; ++ni){
            int o = ob*64 + ni*16 + mr;
            int base = ((o*256 + c0)*dl + d)*2;
            #pragma unroll
            for (int cc = 0; cc < 4; ++cc){
                bf_[ni][2*cc]   = (short)f2bf(wF[base]);
                bf_[ni][2*cc+1] = (short)f2bf(wF[base+1]);
                base += 2*dl;
            }
        }
        #pragma unroll
        for (int mi = 0; mi < 2; ++mi)
            #pragma unroll
            for (int ni = 0; ni < 4; ++ni)
                acc[mi][ni] = __builtin_amdgcn_mfma_f32_16x16x32_bf16(af[mi], bf_[ni], acc[mi][ni], 0,0,0);
    }
    #pragma unroll
    for (int mi = 0; mi < 2; ++mi)
        #pragma unroll
        for (int ni = 0; ni < 4; ++ni)
            #pragma unroll
            for (int r = 0; r < 4; ++r){
                int b = wv2*32 + mi*16 + kg*4 + r;
                int o = ob*64 + ni*16 + mr;
                unsafeAtomicAdd(outS + (d*128 + b)*256 + o, acc[mi][ni][r]);
            }
}

// ---------------------------------------------------------------------------
// Finalize: A_{l+1}[i] = bf16(relu(S_l[i]) / 16)
__global__ __launch_bounds__(256) void fin_kernel(const float* __restrict__ S,
        unsigned short* __restrict__ A, int n){
    int i = (blockIdx.x*256 + threadIdx.x)*4;
    if (i + 3 < n){
        float4 v = *(const float4*)(S + i);
        unsigned short r0 = f2bf(fmaxf(v.x,0.f)*0.0625f);
        unsigned short r1 = f2bf(fmaxf(v.y,0.f)*0.0625f);
        unsigned short r2 = f2bf(fmaxf(v.z,0.f)*0.0625f);
        unsigned short r3 = f2bf(fmaxf(v.w,0.f)*0.0625f);
        unsigned int lo = (unsigned int)r0 | ((unsigned int)r1 << 16);
        unsigned int hi = (unsigned int)r2 | ((unsigned int)r3 << 16);
        uint2 u; u.x = lo; u.y = hi;
        *(uint2*)(A + i) = u;
    }
}

// ---------------------------------------------------------------------------
__global__ void epi_kernel(const float* __restrict__ S9, const float* __restrict__ beta,
                           float* __restrict__ out){
    int b = blockIdx.x;
    int lane = threadIdx.x;
    float accv[OUT_];
    #pragma unroll
    for (int o = 0; o < OUT_; ++o) accv[o] = 0.f;
    for (int h = lane; h < 256; h += 64){
        float y = fmaxf(S9[b*256 + h], 0.f) * 0.0625f;
        #pragma unroll
        for (int o = 0; o < OUT_; ++o)
            accv[o] += y * beta[h*OUT_ + o];
    }
    #pragma unroll
    for (int off = 32; off > 0; off >>= 1){
        #pragma unroll
        for (int o = 0; o < OUT_; ++o)
            accv[o] += __shfl_down(accv[o], off, 64);
    }
    if (lane == 0){
        #pragma unroll
        for (int o = 0; o < OUT_; ++o)
            out[b*OUT_ + o] = accv[o] * (1.f/256.f);
    }
}

// ---------------------------------------------------------------------------
extern "C" void kernel_launch(void* const* d_in, const int* in_sizes, int n_in,
                              void* d_out, int out_size, void* d_ws, size_t ws_size,
                              hipStream_t stream) {
    (void)in_sizes; (void)n_in; (void)out_size; (void)ws_size;
    char* wsb = (char*)d_ws;
    char* base1 = wsb + 512;                      // 33.55 MB: A1, then A3..A9,S8,S9
    unsigned short* A1 = (unsigned short*)(base1);
    unsigned short* A3 = (unsigned short*)(base1);
    unsigned short* A4 = (unsigned short*)(base1 + 8388608);
    unsigned short* A5 = (unsigned short*)(base1 + 12582912);
    unsigned short* A6 = (unsigned short*)(base1 + 14680064);
    unsigned short* A7 = (unsigned short*)(base1 + 15728640);
    unsigned short* A8 = (unsigned short*)(base1 + 16252928);
    unsigned short* A9 = (unsigned short*)(base1 + 16515072);
    float* S8 = (float*)(base1 + 16646144);       // 262,144 B
    float* S9 = (float*)(base1 + 16908288);       // 131,072 B
    unsigned short* A2 = (unsigned short*)(wsb + 512 + 33554432); // 16.78 MB

    const float* x    = (const float*)d_in[0];
    const float* w0   = (const float*)d_in[1];
    const float* beta = (const float*)d_in[11];

    l0_kernel<<<512, 256, 0, stream>>>(x, w0, A1);

    // l1: dl=256, dgN=32, MT=8 (no b-split). grid = 1*32*16 = 512
    layer4_k<8,2><<<512, 256, 0, stream>>>(A1, (const float*)d_in[2], A2, 256, 32);
    // A1 dead; zero tail accumulators S8,S9
    hipMemsetAsync(base1 + 16646144, 0, 393216, stream);
    // l2: dl=128, dgN=16, MT=8. grid = 256
    layer4_k<8,2><<<256, 256, 0, stream>>>(A2, (const float*)d_in[3], A3, 128, 16);
    // l3: dl=64, dgN=8, MT=4 (bsplit 2). grid = 2*8*16 = 256
    layer4_k<4,2><<<256, 256, 0, stream>>>(A3, (const float*)d_in[4], A4, 64, 8);
    // l4: dl=32, dgN=4, MT=2 (bsplit 4). grid = 256
    layer4_k<2,2><<<256, 256, 0, stream>>>(A4, (const float*)d_in[5], A5, 32, 4);
    // l5: dl=16, dgN=2, MT=1 (bsplit 8). grid = 256
    layer4_k<1,2><<<256, 256, 0, stream>>>(A5, (const float*)d_in[6], A6, 16, 2);
    // l6: dl=8, dgN=1, MT=1 (bsplit 8). grid = 128
    layer4_k<1,2><<<128, 256, 0, stream>>>(A6, (const float*)d_in[7], A7, 8, 1);
    // l7: dl=4, DT=4 (DPW=1), dgN=1, MT=1. grid = 128
    layer4_k<1,1><<<128, 256, 0, stream>>>(A7, (const float*)d_in[8], A8, 4, 1);
    // l8, l9: tail (atomic fp32 + fin)
    tail_k<<<128, 256, 0, stream>>>(A8, (const float*)d_in[9], S8, 2, 16);
    fin_kernel<<<64, 256, 0, stream>>>(S8, A9, 65536);
    tail_k<<<64, 256, 0, stream>>>(A9, (const float*)d_in[10], S9, 1, 16);
    epi_kernel<<<128, 64, 0, stream>>>(S9, beta, (float*)d_out);
}